// Round 1
// baseline (103.908 us; speedup 1.0000x reference)
//
#include <hip/hip_runtime.h>

namespace {
constexpr int P       = 4096;   // 16*16*16 voxels
constexpr int KC      = 4;      // label channels
constexpr int SLICES  = 11;     // di in [-5, 5]
constexpr int TOT     = 2 * P * SLICES;   // 90112 threads
constexpr int BLOCK   = 256;
constexpr int NBLK    = TOT / BLOCK;      // 352 (exact)
constexpr int WS_STRIDE = 32;   // floats per batch entry in ws (128 B, own cacheline)
}

__global__ void init_ws_k(float* __restrict__ ws) {
    int t = threadIdx.x;
    if (t < 64) ws[t] = 0.0f;
}

__global__ __launch_bounds__(BLOCK) void sncut_main(
        const float* __restrict__ labels,
        const float* __restrict__ inputs,
        float* __restrict__ ws) {
    const int g     = blockIdx.x * BLOCK + threadIdx.x;   // grid is exact, g < TOT
    const int v     = g / SLICES;
    const int slice = g - v * SLICES;
    const int n     = v >> 12;          // v / 4096
    const int p     = v & (P - 1);
    const int i     = p >> 8;
    const int j     = (p >> 4) & 15;
    const int kz    = p & 15;
    const int di    = slice - 5;
    const int ii    = i + di;

    const float* __restrict__ inp = inputs + n * P;
    const float* __restrict__ A   = labels + n * KC * P;

    float s_w = 0.f, s_k0 = 0.f, s_k1 = 0.f, s_k2 = 0.f, s_k3 = 0.f;

    if (ii >= 0 && ii < 16) {
        const float Ip  = inp[p];
        const int   di2 = di * di;
        const int jlo = (j  < 5) ? -j        : -5;
        const int jhi = (j  > 10) ? (15 - j) :  5;
        const int klo = (kz < 5) ? -kz       : -5;
        const int khi = (kz > 10) ? (15 - kz):  5;
        for (int dj = jlo; dj <= jhi; ++dj) {
            const int sq2 = di2 + dj * dj;
            if (sq2 > 25) continue;
            const int qb = p + di * 256 + dj * 16;
            for (int dk = klo; dk <= khi; ++dk) {
                const int sqd = sq2 + dk * dk;
                if (sqd > 25) continue;
                const int   q = qb + dk;
                const float d = Ip - inp[q];
                // W_X * W_I = exp(-sqd/4 - d^2/10)
                const float w = __expf(-0.25f * (float)sqd - 0.1f * d * d);
                s_w  += w;
                s_k0 += w * A[q];
                s_k1 += w * A[P + q];
                s_k2 += w * A[2 * P + q];
                s_k3 += w * A[3 * P + q];
            }
        }
    }

    // per-thread partials: num_k = A[k,p]*s_k, den_k = A[k,p]*s_w
    float vals[8];
    {
        const float a0 = A[p];
        const float a1 = A[P + p];
        const float a2 = A[2 * P + p];
        const float a3 = A[3 * P + p];
        vals[0] = a0 * s_k0;
        vals[1] = a1 * s_k1;
        vals[2] = a2 * s_k2;
        vals[3] = a3 * s_k3;
        vals[4] = a0 * s_w;
        vals[5] = a1 * s_w;
        vals[6] = a2 * s_w;
        vals[7] = a3 * s_w;
    }

    // wave (64-lane) shuffle reduction — each wave is entirely within one n
    // (n changes at g = 45056 = 704*64, wave-aligned)
    #pragma unroll
    for (int off = 32; off >= 1; off >>= 1) {
        #pragma unroll
        for (int t = 0; t < 8; ++t)
            vals[t] += __shfl_down(vals[t], off, 64);
    }

    __shared__ float red[4][8];
    const int lane = threadIdx.x & 63;
    const int wid  = threadIdx.x >> 6;
    if (lane == 0) {
        #pragma unroll
        for (int t = 0; t < 8; ++t) red[wid][t] = vals[t];
    }
    __syncthreads();
    if (threadIdx.x < 8) {
        // whole block shares one n (n changes at block 176 boundary)
        const float s = red[0][threadIdx.x] + red[1][threadIdx.x]
                      + red[2][threadIdx.x] + red[3][threadIdx.x];
        atomicAdd(&ws[n * WS_STRIDE + threadIdx.x], s);
    }
}

__global__ void finalize_k(const float* __restrict__ ws, float* __restrict__ out) {
    const int n = threadIdx.x;
    if (n < 2) {
        const float* w = ws + n * WS_STRIDE;
        float loss = 0.f;
        #pragma unroll
        for (int t = 0; t < 4; ++t)
            loss += w[t] / (w[4 + t] + 1e-8f);
        out[n] = (float)KC - loss;
    }
}

extern "C" void kernel_launch(void* const* d_in, const int* in_sizes, int n_in,
                              void* d_out, int out_size, void* d_ws, size_t ws_size,
                              hipStream_t stream) {
    const float* labels = (const float*)d_in[0];   // (2,4,16,16,16)
    const float* inputs = (const float*)d_in[1];   // (2,1,16,16,16)
    float* ws  = (float*)d_ws;
    float* out = (float*)d_out;                    // (2,) float32

    hipLaunchKernelGGL(init_ws_k,  dim3(1),    dim3(64),    0, stream, ws);
    hipLaunchKernelGGL(sncut_main, dim3(NBLK), dim3(BLOCK), 0, stream, labels, inputs, ws);
    hipLaunchKernelGGL(finalize_k, dim3(1),    dim3(64),    0, stream, ws, out);
}

// Round 2
// 83.658 us; speedup vs baseline: 1.2421x; 1.2421x over previous
//
#include <hip/hip_runtime.h>

namespace {
constexpr int P        = 4096;            // 16*16*16 voxels
constexpr int KC       = 4;               // label channels
constexpr int NS       = 81;              // (di,dj) pairs with di^2+dj^2 <= 25
constexpr int BLOCK    = 256;
constexpr int PER_N    = NS * P;          // 331776
constexpr int BLK_N    = PER_N / BLOCK;   // 1296 (exact)
constexpr int NBLK     = 2 * BLK_N;       // 2592

struct Tab {
    signed char di[NS], dj[NS], ir[NS], sq2[NS];
};
constexpr Tab make_tab() {
    Tab t{};
    int idx = 0;
    for (int a = -5; a <= 5; ++a)
        for (int b = -5; b <= 5; ++b) {
            int s2 = a * a + b * b;
            if (s2 <= 25) {
                t.di[idx] = (signed char)a;
                t.dj[idx] = (signed char)b;
                int rem = 25 - s2, r = 0;
                while ((r + 1) * (r + 1) <= rem) ++r;
                t.ir[idx]  = (signed char)r;
                t.sq2[idx] = (signed char)s2;
                ++idx;
            }
        }
    return t;
}
}

__device__ constexpr Tab TAB = make_tab();

// Thread = (n, s, p): lanes share (di,dj) slice s, consecutive p -> coalesced
// loads, uniform trip count. Per-block 8-value reduction -> partials slot
// (plain stores; no init kernel needed since every block writes its slot).
__global__ __launch_bounds__(BLOCK) void sncut_main(
        const float* __restrict__ labels,
        const float* __restrict__ inputs,
        float* __restrict__ partials) {
    const int b     = blockIdx.x;
    const int n     = (b >= BLK_N) ? 1 : 0;
    const int local = (b - n * BLK_N) * BLOCK + threadIdx.x;  // [0, PER_N)
    const int s     = local >> 12;          // / 4096  (uniform per block)
    const int p     = local & (P - 1);

    const int di  = TAB.di[s];
    const int dj  = TAB.dj[s];
    const int ir  = TAB.ir[s];
    const int sq2 = TAB.sq2[s];

    const int i  = p >> 8;
    const int j  = (p >> 4) & 15;
    const int kz = p & 15;
    const int ii = i + di;
    const int jj = j + dj;

    const float* __restrict__ inp = inputs + n * P;
    const float* __restrict__ A   = labels + n * KC * P;

    float s_w = 0.f, s_k0 = 0.f, s_k1 = 0.f, s_k2 = 0.f, s_k3 = 0.f;

    if ((unsigned)ii < 16u && (unsigned)jj < 16u) {
        const float Ip   = inp[p];
        const int   base = p + di * 256 + dj * 16;
        const int   lo   = (-kz > -ir) ? -kz : -ir;
        const int   hi   = (15 - kz < ir) ? (15 - kz) : ir;
        for (int dk = lo; dk <= hi; ++dk) {
            const int   q = base + dk;
            const float d = Ip - inp[q];
            // exp(-sqd/4 - (Ip-Iq)^2/10)
            const float w = __expf(-0.25f * (float)(sq2 + dk * dk) - 0.1f * d * d);
            s_w  += w;
            s_k0 += w * A[q];
            s_k1 += w * A[P + q];
            s_k2 += w * A[2 * P + q];
            s_k3 += w * A[3 * P + q];
        }
    }

    float vals[8];
    {
        const float a0 = A[p];
        const float a1 = A[P + p];
        const float a2 = A[2 * P + p];
        const float a3 = A[3 * P + p];
        vals[0] = a0 * s_k0;   // numerator partials
        vals[1] = a1 * s_k1;
        vals[2] = a2 * s_k2;
        vals[3] = a3 * s_k3;
        vals[4] = a0 * s_w;    // denominator partials (symmetry of W)
        vals[5] = a1 * s_w;
        vals[6] = a2 * s_w;
        vals[7] = a3 * s_w;
    }

    // 64-lane wave reduction (block is entirely within one n)
    #pragma unroll
    for (int off = 32; off >= 1; off >>= 1) {
        #pragma unroll
        for (int t = 0; t < 8; ++t)
            vals[t] += __shfl_down(vals[t], off, 64);
    }

    __shared__ float red[4][8];
    const int lane = threadIdx.x & 63;
    const int wid  = threadIdx.x >> 6;
    if (lane == 0) {
        #pragma unroll
        for (int t = 0; t < 8; ++t) red[wid][t] = vals[t];
    }
    __syncthreads();
    if (threadIdx.x < 8) {
        partials[b * 8 + threadIdx.x] =
            red[0][threadIdx.x] + red[1][threadIdx.x] +
            red[2][threadIdx.x] + red[3][threadIdx.x];
    }
}

__global__ __launch_bounds__(256) void finalize_k(
        const float* __restrict__ partials, float* __restrict__ out) {
    __shared__ float sm[2][256];
    const int t  = threadIdx.x;
    const int c  = t & 7;
    const int g2 = t >> 3;      // 32 groups
    float a0 = 0.f, a1 = 0.f;
    for (int b = g2; b < NBLK; b += 32) {
        const float v = partials[b * 8 + c];
        if (b < BLK_N) a0 += v; else a1 += v;
    }
    sm[0][t] = a0;
    sm[1][t] = a1;
    __syncthreads();
    if (t < 16) {
        const int n = t >> 3, cc = t & 7;
        float sacc = 0.f;
        for (int k = 0; k < 32; ++k) sacc += sm[n][cc + 8 * k];
        sm[n][cc] = sacc;
    }
    __syncthreads();
    if (t < 2) {
        float loss = 0.f;
        #pragma unroll
        for (int k = 0; k < 4; ++k)
            loss += sm[t][k] / (sm[t][4 + k] + 1e-8f);
        out[t] = (float)KC - loss;
    }
}

extern "C" void kernel_launch(void* const* d_in, const int* in_sizes, int n_in,
                              void* d_out, int out_size, void* d_ws, size_t ws_size,
                              hipStream_t stream) {
    const float* labels = (const float*)d_in[0];   // (2,4,16,16,16)
    const float* inputs = (const float*)d_in[1];   // (2,1,16,16,16)
    float* partials = (float*)d_ws;                // NBLK*8 floats = 81 KB
    float* out      = (float*)d_out;               // (2,) float32

    hipLaunchKernelGGL(sncut_main, dim3(NBLK), dim3(BLOCK), 0, stream,
                       labels, inputs, partials);
    hipLaunchKernelGGL(finalize_k, dim3(1), dim3(256), 0, stream,
                       partials, out);
}